// Round 12
// baseline (214.768 us; speedup 1.0000x reference)
//
#include <hip/hip_runtime.h>

// CompanionSSM: 256 blocks (1 head), 512 thr = 8 waves, Blelloch scan with
// RECOMPUTED R (no per-chunk R storage) -> LDS 64KB -> 2 blocks/CU.
//  pass1: wave w, chunks 8w..8w+7: load (float4+qtr), UB[j] in regs, R=V@U
//         (f32), local step B<-T@B+R; after chunk 7, stepped B (group Rsum)
//         pk -> Gsum[w].
//  pass2: wave 0: 8 steps with T8 frags (3 hi/lo-split MFMA squarings);
//         entering group states written in place over the Rsums.
//  pass3: wave w: seed from Gsum[w]; per chunk Y = Toep@UB[j] + W@S (qtr
//         back, full-line float4 stores); j<7: recompute R=V@UB[j] (8 MFMAs,
//         MFMA pipe at 5% -> free) and step B<-T@B+R.  u read ONCE.
// Serial path 8+8+7 steps (vs r7's 64) AND 16 waves/CU (vs r11's 8):
// the two proven levers combined.  2 main barriers.
// LDS 65536 exact: Gsum 16KB (alias scrA) + G-upper/scrB 16KB +
// FV/FW/FK 24KB + FT8 8KB (phi/kv alias FT8 head).

#define NKH 256
#define KD  64
#define SL  4096
#define DM  1024

typedef __attribute__((ext_vector_type(8))) short short8;
typedef __attribute__((ext_vector_type(4))) float floatx4;

#define GSUM_OFF  0          // 8 x 2KB group slots (pass1+)
#define SCRA_OFF  0          // f32 64x64 T/T4 (prep only, aliases Gsum)
#define SCRB_OFF  16384      // f32 64x64 T2/T8 (= dead G rows 64..127)
#define FV_OFF    32768
#define FW_OFF    40960
#define FK_OFF    49152
#define FT8_OFF   57344
#define PHI_OFF   57344      // f32[128], dead before FT8 write
#define KV_OFF    57856      // f32[64]
#define LDS_TOTAL 65536

static __device__ __forceinline__ unsigned pack_bf16(float a, float b) {
  union { float f; unsigned u; } ua, ub;
  ua.f = a; ub.f = b;
  return __builtin_amdgcn_perm(ub.u + 0x8000u, ua.u + 0x8000u, 0x07060302u);
}
static __device__ __forceinline__ unsigned short f2bfru(float x) {
  union { float f; unsigned u; } v; v.f = x;
  return (unsigned short)((v.u + 0x8000u) >> 16);
}
static __device__ __forceinline__ float bflo(unsigned d) {
  union { unsigned u; float f; } v; v.u = d << 16; return v.f;
}
static __device__ __forceinline__ float bfhi(unsigned d) {
  union { unsigned u; float f; } v; v.u = d & 0xffff0000u; return v.f;
}
static __device__ __forceinline__ float bf2f(unsigned short s) {
  union { unsigned u; float f; } v; v.u = ((unsigned)s) << 16; return v.f;
}
static __device__ __forceinline__ float wredsum(float x) {
#pragma unroll
  for (int off = 32; off; off >>= 1) x += __shfl_xor(x, off, 64);
  return x;
}
// 4x4 transpose across a DPP quad (lanes 4k..4k+3, c = lane&3).
static __device__ __forceinline__ float4 qtr(float4 v, int c) {
  const bool c1 = (c & 1) != 0, c2 = (c & 2) != 0;
  float a01 = __shfl_xor(v.y, 1, 64), a10 = __shfl_xor(v.x, 1, 64);
  float a23 = __shfl_xor(v.w, 1, 64), a32 = __shfl_xor(v.z, 1, 64);
  float t0 = c1 ? a01 : v.x, t1 = c1 ? v.y : a10;
  float t2 = c1 ? a23 : v.z, t3 = c1 ? v.w : a32;
  float b02 = __shfl_xor(t2, 2, 64), b20 = __shfl_xor(t0, 2, 64);
  float b13 = __shfl_xor(t3, 2, 64), b31 = __shfl_xor(t1, 2, 64);
  float4 r;
  r.x = c2 ? b02 : t0; r.y = c2 ? b13 : t1;
  r.z = c2 ? t2 : b20; r.w = c2 ? t3 : b31;
  return r;
}
// frag-major 16B-group byte offset for 64x64 bf16
static __device__ __forceinline__ int fmoff(int row, int colg) {
  return ((((row >> 4) * 2 + (colg >> 5)) * 64 + ((colg >> 3) & 3) * 16 + (row & 15)) << 4);
}

// pk (C-layout packed) -> B-frag conversion via 16 shfl (r0-r11 verified)
#define CONV_PK(PK) do { \
  union { short8 v; unsigned uu[4]; } nb0_, nb1_; \
  unsigned xa_, xb_; \
  xa_ = __shfl(PK[0][0], srcA, 64); xb_ = __shfl(PK[1][0], srcA, 64); nb0_.uu[0] = hi ? xb_ : xa_; \
  xa_ = __shfl(PK[0][1], srcA, 64); xb_ = __shfl(PK[1][1], srcA, 64); nb0_.uu[1] = hi ? xb_ : xa_; \
  xa_ = __shfl(PK[0][0], srcB, 64); xb_ = __shfl(PK[1][0], srcB, 64); nb0_.uu[2] = hi ? xb_ : xa_; \
  xa_ = __shfl(PK[0][1], srcB, 64); xb_ = __shfl(PK[1][1], srcB, 64); nb0_.uu[3] = hi ? xb_ : xa_; \
  xa_ = __shfl(PK[2][0], srcA, 64); xb_ = __shfl(PK[3][0], srcA, 64); nb1_.uu[0] = hi ? xb_ : xa_; \
  xa_ = __shfl(PK[2][1], srcA, 64); xb_ = __shfl(PK[3][1], srcA, 64); nb1_.uu[1] = hi ? xb_ : xa_; \
  xa_ = __shfl(PK[2][0], srcB, 64); xb_ = __shfl(PK[3][0], srcB, 64); nb1_.uu[2] = hi ? xb_ : xa_; \
  xa_ = __shfl(PK[2][1], srcB, 64); xb_ = __shfl(PK[3][1], srcB, 64); nb1_.uu[3] = hi ? xb_ : xa_; \
  B0 = nb0_.v; B1 = nb1_.v; \
} while (0)

// one squaring level: DST = SRC @ SRC (64x64 f32, stride 64), hi/lo bf16
// split; 16 tiles = 2 per wave (8 waves).  r1/r11-verified math.
#define SQ_LEVEL(SRC, DST) do { \
  _Pragma("unroll") \
  for (int tt_ = 0; tt_ < 2; ++tt_) { \
    const int rt_ = (2*w + tt_) >> 2, ct_ = (2*w + tt_) & 3; \
    short8 Ah_[2], Al_[2], Bh_[2], Bl_[2]; \
    _Pragma("unroll") \
    for (int kt_ = 0; kt_ < 2; ++kt_) { \
      const float* ap_ = (SRC) + (16*rt_ + n16)*64 + 32*kt_ + 8*quad; \
      union { short8 v; unsigned short us[8]; } ah_, al_, bh_, bl_; \
      _Pragma("unroll") \
      for (int j_ = 0; j_ < 8; ++j_) { \
        float x_ = ap_[j_]; \
        unsigned short hu_ = f2bfru(x_); \
        ah_.us[j_] = (short)hu_; al_.us[j_] = (short)f2bfru(x_ - bf2f(hu_)); \
      } \
      _Pragma("unroll") \
      for (int j_ = 0; j_ < 8; ++j_) { \
        float x_ = (SRC)[(32*kt_ + 8*quad + j_)*64 + 16*ct_ + n16]; \
        unsigned short hu_ = f2bfru(x_); \
        bh_.us[j_] = (short)hu_; bl_.us[j_] = (short)f2bfru(x_ - bf2f(hu_)); \
      } \
      Ah_[kt_] = ah_.v; Al_[kt_] = al_.v; Bh_[kt_] = bh_.v; Bl_[kt_] = bl_.v; \
    } \
    floatx4 d_ = {0.f, 0.f, 0.f, 0.f}; \
    _Pragma("unroll") \
    for (int kt_ = 0; kt_ < 2; ++kt_) { \
      d_ = __builtin_amdgcn_mfma_f32_16x16x32_bf16(Ah_[kt_], Bh_[kt_], d_, 0,0,0); \
      d_ = __builtin_amdgcn_mfma_f32_16x16x32_bf16(Ah_[kt_], Bl_[kt_], d_, 0,0,0); \
      d_ = __builtin_amdgcn_mfma_f32_16x16x32_bf16(Al_[kt_], Bh_[kt_], d_, 0,0,0); \
    } \
    _Pragma("unroll") \
    for (int r_ = 0; r_ < 4; ++r_) \
      (DST)[(16*rt_ + 4*quad + r_)*64 + 16*ct_ + n16] = d_[r_]; \
  } \
} while (0)

// load chunk at row base ROW0: 4 float4/lane, full-line (r7-r11 verified)
#define LOADC(ROW0, L) do { \
  L[0] = *(const float4*)(upb + (size_t)((ROW0) + q8 +     rr) * DM); \
  L[1] = *(const float4*)(upb + (size_t)((ROW0) + q8 + 4 + rr) * DM); \
  L[2] = *(const float4*)(upb + (size_t)((ROW0) + 32 + q8 +     rr) * DM); \
  L[3] = *(const float4*)(upb + (size_t)((ROW0) + 32 + q8 + 4 + rr) * DM); \
} while (0)

// R = V @ UB[J] -> RACC (f32), from frag-major FV (r7-r11 verified)
#define MAKE_R(J, RACC) do { \
  _Pragma("unroll") \
  for (int rt_ = 0; rt_ < 4; ++rt_) { \
    const short8 v0_ = *(const short8*)(lds + FV_OFF + (((rt_*2 + 0)*64 + lane) << 4)); \
    const short8 v1_ = *(const short8*)(lds + FV_OFF + (((rt_*2 + 1)*64 + lane) << 4)); \
    floatx4 r_ = {0.f, 0.f, 0.f, 0.f}; \
    r_ = __builtin_amdgcn_mfma_f32_16x16x32_bf16(v0_, UB[J][0], r_, 0,0,0); \
    RACC[rt_] = __builtin_amdgcn_mfma_f32_16x16x32_bf16(v1_, UB[J][1], r_, 0,0,0); \
  } \
} while (0)

// step: pk = pack(T@B + RACC); then either CONV to B or store to Gsum slot
#define STEP_PK(RACC, PKOUT) do { \
  _Pragma("unroll") \
  for (int rt_ = 0; rt_ < 4; ++rt_) { \
    floatx4 a0_ = __builtin_amdgcn_mfma_f32_16x16x32_bf16(At[rt_][0], B0, RACC[rt_], 0,0,0); \
    floatx4 ac_ = __builtin_amdgcn_mfma_f32_16x16x32_bf16(At[rt_][1], B1, a0_, 0,0,0); \
    PKOUT[rt_][0] = pack_bf16(ac_[0], ac_[1]); \
    PKOUT[rt_][1] = pack_bf16(ac_[2], ac_[3]); \
  } \
} while (0)

// pass1 chunk J from loaded regs L: UB[J] <- transpose/pack; R=V@U; step.
// J<7: B <- stepped; J==7: stepped pk (group Rsum) -> Gsum[w].
#define PRODCHUNK(J, L) do { \
  const float4 W00_ = qtr(L[0], rr), W01_ = qtr(L[1], rr); \
  const float4 W10_ = qtr(L[2], rr), W11_ = qtr(L[3], rr); \
  union { short8 v; unsigned s4[4]; } u0_, u1_; \
  u0_.s4[0] = pack_bf16(W00_.x, W00_.y); u0_.s4[1] = pack_bf16(W00_.z, W00_.w); \
  u0_.s4[2] = pack_bf16(W01_.x, W01_.y); u0_.s4[3] = pack_bf16(W01_.z, W01_.w); \
  u1_.s4[0] = pack_bf16(W10_.x, W10_.y); u1_.s4[1] = pack_bf16(W10_.z, W10_.w); \
  u1_.s4[2] = pack_bf16(W11_.x, W11_.y); u1_.s4[3] = pack_bf16(W11_.z, W11_.w); \
  UB[J][0] = u0_.v; UB[J][1] = u1_.v; \
  floatx4 racc_[4]; \
  MAKE_R(J, racc_); \
  unsigned pk_[4][2]; \
  STEP_PK(racc_, pk_); \
  if ((J) < 7) { CONV_PK(pk_); } \
  else { \
    _Pragma("unroll") \
    for (int rt_ = 0; rt_ < 4; ++rt_) { \
      uint2 pq_; pq_.x = pk_[rt_][0]; pq_.y = pk_[rt_][1]; \
      *(uint2*)(gsumw + rt_*512 + lane*8) = pq_; \
    } \
  } \
} while (0)

// pass3 chunk J: Y = Toep@UB[J] + W@B (store); J<7: recompute R, step B.
#define CONSCHUNK(J) do { \
  _Pragma("unroll") \
  for (int rt_ = 0; rt_ < 4; ++rt_) { \
    const short8 k0_ = *(const short8*)(lds + FK_OFF + (((rt_*2 + 0)*64 + lane) << 4)); \
    const short8 k1_ = *(const short8*)(lds + FK_OFF + (((rt_*2 + 1)*64 + lane) << 4)); \
    const short8 w0_ = *(const short8*)(lds + FW_OFF + (((rt_*2 + 0)*64 + lane) << 4)); \
    const short8 w1_ = *(const short8*)(lds + FW_OFF + (((rt_*2 + 1)*64 + lane) << 4)); \
    floatx4 ty_ = {0.f, 0.f, 0.f, 0.f}; \
    ty_ = __builtin_amdgcn_mfma_f32_16x16x32_bf16(k0_, UB[J][0], ty_, 0,0,0); \
    ty_ = __builtin_amdgcn_mfma_f32_16x16x32_bf16(k1_, UB[J][1], ty_, 0,0,0); \
    ty_ = __builtin_amdgcn_mfma_f32_16x16x32_bf16(w0_, B0, ty_, 0,0,0); \
    ty_ = __builtin_amdgcn_mfma_f32_16x16x32_bf16(w1_, B1, ty_, 0,0,0); \
    float4 yv_; yv_.x = ty_[0]; yv_.y = ty_[1]; yv_.z = ty_[2]; yv_.w = ty_[3]; \
    const float4 tw_ = qtr(yv_, rr); \
    *(float4*)(opb + (size_t)((c0 + (J))*64 + 16*rt_ + 4*quad + rr) * DM) = tw_; \
  } \
  if ((J) < 7) { \
    floatx4 racc_[4]; \
    MAKE_R(J, racc_); \
    unsigned pk_[4][2]; \
    STEP_PK(racc_, pk_); \
    CONV_PK(pk_); \
  } \
} while (0)

__global__ __launch_bounds__(512, 4) void fused_kernel(
    const float* __restrict__ u, const float* __restrict__ ga,
    const float* __restrict__ gb, const float* __restrict__ gc,
    float* __restrict__ out)
{
  __shared__ __align__(16) char lds[LDS_TOTAL];
  unsigned short* G = (unsigned short*)lds;     // rows 64..127 -> [16384,32768)
  float* phi  = (float*)(lds + PHI_OFF);
  float* kv   = (float*)(lds + KV_OFF);
  float* scrA = (float*)(lds + SCRA_OFF);
  float* scrB = (float*)(lds + SCRB_OFF);

  const int i = blockIdx.x;
  const int h = 8 * (i & 31) + (i >> 5);        // co-line heads -> same XCD
  const int t = threadIdx.x;
  const int w = t >> 6, lane = t & 63;
  const int n16 = lane & 15, quad = lane >> 4;
  const int rr = lane & 3, q8 = quad * 8, bqi = (lane >> 2) & 3;

  // ---------------- prep chains (waves 0,1; no in-loop reductions) --------
  if (w < 2) {
    const float av = ga[h*KD + lane];
    const float an = av / wredsum(fabsf(av));   // mean(|rowsum|) >> eps
    if (w == 1) {
      phi[lane] = gc[h*KD + lane];              // phi[0..63] = c
      float g = an;                             // g_64 = A^64 e0 = a_n
      for (int p = 64; p < 128; ++p) {
        G[(64 + lane)*128 + (p - 64)] = f2bfru(g);   // T col m = g_{64+m}
        const float top = __shfl(g, 63, 64);
        const float gm1 = __shfl_up(g, 1, 64);
        g = (lane > 0 ? gm1 : 0.0f) + an * top;
      }
    } else {
      float v = gb[h*KD + lane];                // v_j = A^j b
      for (int j = 0; j < KD; ++j) {
        G[(64 + lane)*128 + 64 + (63 - j)] = f2bfru(v);  // V col m = v_{63-m}
        const float top = __shfl(v, 63, 64);
        const float vm1 = __shfl_up(v, 1, 64);
        v = (lane > 0 ? vm1 : 0.0f) + an * top;
      }
    }
  }
  __syncthreads();

  // ------- deferred dot products: phi[64..127] and kv[0..63] -------
  if (t < 128) {
    float acc = 0.f;
    for (int n = 0; n < 64; ++n)
      acc += phi[n] * bf2f(G[(64 + n)*128 + t]);
    if (t < 64) phi[64 + t] = acc;      // phi[p] = c . g_p
    else        kv[127 - t] = acc;      // kv[j] = c . v_j
  }
  __syncthreads();

  // ---- fills: FV copy, FW/FK direct, At (all waves), T -> scrA (f32) ----
  {
    const int f = t >> 6, l = t & 63;           // V frags: 8 x 64 groups
    const int rt = f >> 1, kt = f & 1;
    const int ln = l & 15, lq2 = l >> 4;
    *(uint4*)(lds + FV_OFF + ((f*64 + l) << 4)) =
        *(const uint4*)(G + (64 + 16*rt + ln)*128 + 64 + 32*kt + 8*lq2);
  }
  {
    const int cgi = t >> 6, row = t & 63;       // W/K frags: 64 rows x 8 cg
    const int colg = cgi * 8;
    union { short8 v; unsigned short us[8]; } wb, kb;
#pragma unroll
    for (int jj = 0; jj < 8; ++jj) {
      wb.us[jj] = f2bfru(phi[row + 1 + colg + jj]);
      const int mm = colg + jj;
      kb.us[jj] = (mm <= row) ? f2bfru(kv[row - mm]) : (unsigned short)0;
    }
    *(short8*)(lds + FW_OFF + fmoff(row, colg)) = wb.v;
    *(short8*)(lds + FK_OFF + fmoff(row, colg)) = kb.v;
  }
  short8 At[4][2];
#pragma unroll
  for (int rt = 0; rt < 4; ++rt)
#pragma unroll
    for (int kt = 0; kt < 2; ++kt)
      At[rt][kt] = *(const short8*)(G + (64 + 16*rt + n16)*128 + 32*kt + quad*8);
  for (int idx = t; idx < 4096; idx += 512) {   // T -> scrA f32
    const int row = idx >> 6, col = idx & 63;
    scrA[row*64 + col] = bf2f(G[(64 + row)*128 + col]);
  }
  __syncthreads();

  // ---------------- T8 = ((T^2)^2)^2 via 3 squarings ----------------
  SQ_LEVEL(scrA, scrB);   // T2 (scrB aliases dead G region)
  __syncthreads();
  SQ_LEVEL(scrB, scrA);   // T4
  __syncthreads();
  SQ_LEVEL(scrA, scrB);   // T8
  __syncthreads();
  {                       // At8 frags -> FT8 (one frag per wave)
    const int rt8 = w >> 1, kt8 = w & 1;
    union { short8 v; unsigned short us[8]; } a8;
#pragma unroll
    for (int j = 0; j < 8; ++j)
      a8.us[j] = (short)f2bfru(scrB[(16*rt8 + n16)*64 + 32*kt8 + 8*quad + j]);
    *(short8*)(lds + FT8_OFF + (((rt8*2 + kt8)*64 + lane) << 4)) = a8.v;
  }
  __syncthreads();        // scrA/scrB dead -> Gsum usable

  // ---------------- pass1: 8 chunks/wave, local scan, UB in regs ----------
  const float* upb = u   + (size_t)bqi * ((size_t)SL * DM) + 4*h;
  float*       opb = out + (size_t)bqi * ((size_t)SL * DM) + 4*h;
  const int c0 = 8 * w;                   // wave's first global chunk
  char* gsumw = lds + GSUM_OFF + w * 2048;
  const int srcA = n16 + 16*((2*quad) & 3);
  const int srcB = n16 + 16*((2*quad + 1) & 3);
  const bool hi = (quad >= 2);
  const short8 Z8 = {0,0,0,0,0,0,0,0};
  short8 B0 = Z8, B1 = Z8;
  short8 UB[8][2];

  {
    float4 LA[4], LB[4];
    LOADC(c0*64, LA);
    LOADC((c0 + 1)*64, LB);
    PRODCHUNK(0, LA); LOADC((c0 + 2)*64, LA);
    PRODCHUNK(1, LB); LOADC((c0 + 3)*64, LB);
    PRODCHUNK(2, LA); LOADC((c0 + 4)*64, LA);
    PRODCHUNK(3, LB); LOADC((c0 + 5)*64, LB);
    PRODCHUNK(4, LA); LOADC((c0 + 6)*64, LA);
    PRODCHUNK(5, LB); LOADC((c0 + 7)*64, LB);
    PRODCHUNK(6, LA);
    PRODCHUNK(7, LB);
  }
  __syncthreads();

  // ---------------- pass2: wave 0, 8 steps with T8 ----------------
  if (w == 0) {
    short8 At8[4][2];
#pragma unroll
    for (int rt = 0; rt < 4; ++rt)
#pragma unroll
      for (int kt = 0; kt < 2; ++kt)
        At8[rt][kt] = *(const short8*)(lds + FT8_OFF + (((rt*2 + kt)*64 + lane) << 4));
    B0 = Z8; B1 = Z8;
#pragma unroll 1
    for (int g = 0; g < 8; ++g) {
      char* sp = lds + GSUM_OFF + g * 2048;
      uint2 rb[4];
#pragma unroll
      for (int rt = 0; rt < 4; ++rt) rb[rt] = *(const uint2*)(sp + rt*512 + lane*8);
      asm volatile("" ::: "memory");
      *(short8*)(sp + lane*16)        = B0;   // entering state of group g
      *(short8*)(sp + 1024 + lane*16) = B1;
      unsigned pk[4][2];
#pragma unroll
      for (int rt = 0; rt < 4; ++rt) {
        floatx4 cs;
        cs[0] = bflo(rb[rt].x); cs[1] = bfhi(rb[rt].x);
        cs[2] = bflo(rb[rt].y); cs[3] = bfhi(rb[rt].y);
        floatx4 a0 = __builtin_amdgcn_mfma_f32_16x16x32_bf16(At8[rt][0], B0, cs, 0,0,0);
        floatx4 ac = __builtin_amdgcn_mfma_f32_16x16x32_bf16(At8[rt][1], B1, a0, 0,0,0);
        pk[rt][0] = pack_bf16(ac[0], ac[1]);
        pk[rt][1] = pack_bf16(ac[2], ac[3]);
      }
      CONV_PK(pk);
    }
  }
  __syncthreads();

  // ---------------- pass3: seed + 8 chunks/wave (R recomputed) ------------
  B0 = *(const short8*)(gsumw + lane*16);
  B1 = *(const short8*)(gsumw + 1024 + lane*16);
  CONSCHUNK(0);
  CONSCHUNK(1);
  CONSCHUNK(2);
  CONSCHUNK(3);
  CONSCHUNK(4);
  CONSCHUNK(5);
  CONSCHUNK(6);
  CONSCHUNK(7);
}

// ---------------------------------------------------------------- launch --
extern "C" void kernel_launch(void* const* d_in, const int* in_sizes, int n_in,
                              void* d_out, int out_size, void* d_ws, size_t ws_size,
                              hipStream_t stream)
{
  const float* u = (const float*)d_in[0];
  const float* a = (const float*)d_in[1];
  const float* b = (const float*)d_in[2];
  const float* c = (const float*)d_in[3];
  float* out = (float*)d_out;
  (void)d_ws; (void)ws_size; (void)in_sizes; (void)n_in; (void)out_size;

  fused_kernel<<<NKH, 512, 0, stream>>>(u, a, b, c, out);
}